// Round 1
// baseline (480.229 us; speedup 1.0000x reference)
//
#include <hip/hip_runtime.h>
#include <hip/hip_bf16.h>

// EntropyLoss: x (65536 x 1024) fp32.
//   norm2[j] = sum_i x[i][j]^2         (column sum of squares)
//   p = x / max(sqrt(norm2[col]), 1e-12)
//   out = -(1/R) * sum_ij p * log(p + 1e-8)
//
// Layout trick: block=256 threads, thread t always owns columns 4t..4t+3
// (256 threads * float4 = 1024 cols = exactly one row per block-iteration).
// => per-row access is one fully-coalesced 4KB sweep, and inv_norm for a
// thread's columns fits in 4 registers (no LDS staging).

#define ROWS 65536
#define COLS 1024
#define C4   (COLS / 4)

#define EPS_NORM 1e-12f
#define EPS_LOG  1e-8f

__global__ __launch_bounds__(256) void colnorm2_kernel(
    const float* __restrict__ x, float* __restrict__ norm2, int rows_per_block) {
    const int t = threadIdx.x;
    const size_t r0 = (size_t)blockIdx.x * rows_per_block;
    const float4* xr = reinterpret_cast<const float4*>(x) + r0 * C4 + t;

    float4 acc = make_float4(0.f, 0.f, 0.f, 0.f);
    #pragma unroll 8
    for (int r = 0; r < rows_per_block; ++r) {
        float4 v = xr[(size_t)r * C4];
        acc.x = fmaf(v.x, v.x, acc.x);
        acc.y = fmaf(v.y, v.y, acc.y);
        acc.z = fmaf(v.z, v.z, acc.z);
        acc.w = fmaf(v.w, v.w, acc.w);
    }
    float* dst = norm2 + 4 * t;
    atomicAdd(dst + 0, acc.x);
    atomicAdd(dst + 1, acc.y);
    atomicAdd(dst + 2, acc.z);
    atomicAdd(dst + 3, acc.w);
}

__global__ __launch_bounds__(256) void entropy_kernel(
    const float* __restrict__ x, const float* __restrict__ norm2,
    float* __restrict__ out, int rows_per_block) {
    const int t = threadIdx.x;

    // Per-thread inv-norms for its 4 fixed columns (registers, no LDS).
    float4 s = reinterpret_cast<const float4*>(norm2)[t];
    float4 inv;
    inv.x = 1.0f / fmaxf(sqrtf(s.x), EPS_NORM);
    inv.y = 1.0f / fmaxf(sqrtf(s.y), EPS_NORM);
    inv.z = 1.0f / fmaxf(sqrtf(s.z), EPS_NORM);
    inv.w = 1.0f / fmaxf(sqrtf(s.w), EPS_NORM);

    const size_t r0 = (size_t)blockIdx.x * rows_per_block;
    const float4* xr = reinterpret_cast<const float4*>(x) + r0 * C4 + t;

    float acc = 0.f;
    #pragma unroll 4
    for (int r = 0; r < rows_per_block; ++r) {
        float4 v = xr[(size_t)r * C4];
        float px = v.x * inv.x;
        float py = v.y * inv.y;
        float pz = v.z * inv.z;
        float pw = v.w * inv.w;
        acc = fmaf(px, __logf(px + EPS_LOG), acc);
        acc = fmaf(py, __logf(py + EPS_LOG), acc);
        acc = fmaf(pz, __logf(pz + EPS_LOG), acc);
        acc = fmaf(pw, __logf(pw + EPS_LOG), acc);
    }

    // wave-64 butterfly reduce
    #pragma unroll
    for (int o = 32; o > 0; o >>= 1) acc += __shfl_down(acc, o, 64);

    __shared__ float wsum[4];
    if ((t & 63) == 0) wsum[t >> 6] = acc;
    __syncthreads();
    if (t == 0) {
        float b = wsum[0] + wsum[1] + wsum[2] + wsum[3];
        atomicAdd(out, -b * (1.0f / (float)ROWS));  // negate + mean fold
    }
}

extern "C" void kernel_launch(void* const* d_in, const int* in_sizes, int n_in,
                              void* d_out, int out_size, void* d_ws, size_t ws_size,
                              hipStream_t stream) {
    const float* x = (const float*)d_in[0];
    float* out = (float*)d_out;
    float* norm2 = (float*)d_ws;  // 1024 floats = 4 KB

    // ws and d_out are re-poisoned to 0xAA before every timed call.
    hipMemsetAsync(norm2, 0, COLS * sizeof(float), stream);
    hipMemsetAsync(out, 0, sizeof(float), stream);

    // Pass 1: column sums of squares. 1024 blocks * 64 rows.
    colnorm2_kernel<<<1024, 256, 0, stream>>>(x, norm2, ROWS / 1024);

    // Pass 2: entropy sum. 2048 blocks * 32 rows.
    entropy_kernel<<<2048, 256, 0, stream>>>(x, norm2, out, ROWS / 2048);
}

// Round 2
// 412.237 us; speedup vs baseline: 1.1649x; 1.1649x over previous
//
#include <hip/hip_runtime.h>
#include <hip/hip_bf16.h>

// EntropyLoss: x (65536 x 1024) fp32.
//   norm2[j] = sum_i x[i][j]^2
//   p = x / max(sqrt(norm2[col]), 1e-12)
//   out = -(1/R) * sum_ij p * log(p + 1e-8)
//
// R1 changes vs R0:
//  * No long same-address atomic chains (R0: 1024-deep chains in colnorm,
//    2048-deep single-address chain in entropy => ~150ns/op serialized =
//    the entire 480us). colnorm uses 64 hierarchical slots (depth 32);
//    entropy writes per-block partials, reduced by a tiny final kernel.
//  * Grid-stride row sweep: at any instant the whole grid reads one
//    contiguous 8MB window (m13 copy pattern), not 1024 scattered streams.
//  * Fixed-column trick kept: thread t owns cols 4t..4t+3 in EVERY block
//    (block row-offset is a multiple of full rows), inv_norm in 4 regs.

#define ROWS 65536
#define COLS 1024
#define C4   (COLS / 4)
#define GRID1 2048
#define ITERS (ROWS / GRID1)   // 32
#define NSLOT 64

#define EPS_NORM 1e-12f
#define EPS_LOG  1e-8f

// ws layout (floats):
//   part    : [NSLOT][COLS]   @ 0        (256 KB, atomic, zero-init)
//   inv     : [COLS]          @ 65536    (4 KB)
//   bpart   : [GRID1]         @ 66560    (8 KB)
#define WS_PART  0
#define WS_INV   (NSLOT * COLS)
#define WS_BPART (WS_INV + COLS)
#define WS_FLOATS (WS_BPART + GRID1)

__global__ __launch_bounds__(256) void colnorm2_kernel(
    const float* __restrict__ x, float* __restrict__ part) {
    const int t = threadIdx.x;
    const float4* xr = reinterpret_cast<const float4*>(x)
                     + (size_t)blockIdx.x * C4 + t;

    float4 acc = make_float4(0.f, 0.f, 0.f, 0.f);
    #pragma unroll 4
    for (int k = 0; k < ITERS; ++k) {
        float4 v = xr[(size_t)k * GRID1 * C4];
        acc.x = fmaf(v.x, v.x, acc.x);
        acc.y = fmaf(v.y, v.y, acc.y);
        acc.z = fmaf(v.z, v.z, acc.z);
        acc.w = fmaf(v.w, v.w, acc.w);
    }
    float* dst = part + (blockIdx.x & (NSLOT - 1)) * COLS + 4 * t;
    atomicAdd(dst + 0, acc.x);   // chain depth GRID1/NSLOT = 32
    atomicAdd(dst + 1, acc.y);
    atomicAdd(dst + 2, acc.z);
    atomicAdd(dst + 3, acc.w);
}

// grid 4 x 256: column j sums its NSLOT partials, stores 1/max(sqrt,eps).
__global__ __launch_bounds__(256) void finalize_norm_kernel(
    const float* __restrict__ part, float* __restrict__ inv) {
    const int j = blockIdx.x * 256 + threadIdx.x;
    float s = 0.f;
    #pragma unroll 16
    for (int r = 0; r < NSLOT; ++r) s += part[r * COLS + j];
    inv[j] = 1.0f / fmaxf(sqrtf(s), EPS_NORM);
}

__global__ __launch_bounds__(256) void entropy_kernel(
    const float* __restrict__ x, const float* __restrict__ invn,
    float* __restrict__ bpart) {
    const int t = threadIdx.x;
    const float4 inv = reinterpret_cast<const float4*>(invn)[t];
    const float4* xr = reinterpret_cast<const float4*>(x)
                     + (size_t)blockIdx.x * C4 + t;

    float acc = 0.f;
    #pragma unroll 2
    for (int k = 0; k < ITERS; ++k) {
        float4 v = xr[(size_t)k * GRID1 * C4];
        float px = v.x * inv.x;
        float py = v.y * inv.y;
        float pz = v.z * inv.z;
        float pw = v.w * inv.w;
        acc = fmaf(px, __logf(px + EPS_LOG), acc);
        acc = fmaf(py, __logf(py + EPS_LOG), acc);
        acc = fmaf(pz, __logf(pz + EPS_LOG), acc);
        acc = fmaf(pw, __logf(pw + EPS_LOG), acc);
    }

    #pragma unroll
    for (int o = 32; o > 0; o >>= 1) acc += __shfl_down(acc, o, 64);

    __shared__ float wsum[4];
    if ((t & 63) == 0) wsum[t >> 6] = acc;
    __syncthreads();
    if (t == 0) bpart[blockIdx.x] = wsum[0] + wsum[1] + wsum[2] + wsum[3];
}

// 1 block x 256: reduce GRID1 block partials, write final scalar.
__global__ __launch_bounds__(256) void final_reduce_kernel(
    const float* __restrict__ bpart, float* __restrict__ out) {
    const int t = threadIdx.x;
    float a = 0.f;
    #pragma unroll 8
    for (int k = 0; k < GRID1 / 256; ++k) a += bpart[k * 256 + t];

    #pragma unroll
    for (int o = 32; o > 0; o >>= 1) a += __shfl_down(a, o, 64);

    __shared__ float wsum[4];
    if ((t & 63) == 0) wsum[t >> 6] = a;
    __syncthreads();
    if (t == 0) out[0] = -(wsum[0] + wsum[1] + wsum[2] + wsum[3])
                         * (1.0f / (float)ROWS);
}

extern "C" void kernel_launch(void* const* d_in, const int* in_sizes, int n_in,
                              void* d_out, int out_size, void* d_ws, size_t ws_size,
                              hipStream_t stream) {
    const float* x = (const float*)d_in[0];
    float* out = (float*)d_out;
    float* ws = (float*)d_ws;
    float* part  = ws + WS_PART;
    float* inv   = ws + WS_INV;
    float* bpart = ws + WS_BPART;

    // part is accumulated atomically -> must start at zero (ws is 0xAA-poisoned).
    hipMemsetAsync(part, 0, NSLOT * COLS * sizeof(float), stream);

    colnorm2_kernel<<<GRID1, 256, 0, stream>>>(x, part);
    finalize_norm_kernel<<<COLS / 256, 256, 0, stream>>>(part, inv);
    entropy_kernel<<<GRID1, 256, 0, stream>>>(x, inv, bpart);
    final_reduce_kernel<<<1, 256, 0, stream>>>(bpart, out);
}

// Round 4
// 404.683 us; speedup vs baseline: 1.1867x; 1.0187x over previous
//
#include <hip/hip_runtime.h>
#include <hip/hip_bf16.h>

// EntropyLoss: x (65536 x 1024) fp32.
//   norm2[j] = sum_i x[i][j]^2 ; n_j = max(sqrt(norm2), 1e-12)
//   out = -(1/R) * sum_ij (x/n) * log(x/n + 1e-8)
//
// R2 (resubmitted in R3 after broker timeout): ONE PASS. Using
// log(p+1e-8) ~= log p = log x - log n (error ~eps per element => ~1e-5 on
// the scalar output, threshold 0.38), the loss factorizes into per-column
// sufficient statistics:
//   S1 = sum x, S2 = sum x^2, S3 = sum x*log(x)
//   out = -(1/R) * sum_j (S3_j - log(n_j)*S1_j) / n_j
// => single 268MB sweep instead of two (R1 profile showed both kernels
// <158us each and ~240us of dur_us is harness reset traffic: 1GiB ws
// poison + 256MiB input restore, outside our control).

#define ROWS  65536
#define COLS  1024
#define C4    (COLS / 4)
#define GRID  2048
#define ITERS (ROWS / GRID)   // 32
#define NSLOT 64

#define EPS_NORM 1e-12f

// ws layout (floats):
//   part : [NSLOT][3][COLS] @ 0          (768 KB, atomic, zero-init)
//   bpart: [4]              @ NSLOT*3*COLS
#define WS_PART   0
#define WS_BPART  (NSLOT * 3 * COLS)

__global__ __launch_bounds__(256) void fused_stats_kernel(
    const float* __restrict__ x, float* __restrict__ part) {
    const int t = threadIdx.x;
    // thread t owns cols 4t..4t+3 in every row; rows grid-strided so the
    // whole grid sweeps one contiguous 8MB window at a time.
    const float4* xr = reinterpret_cast<const float4*>(x)
                     + (size_t)blockIdx.x * C4 + t;

    float4 s1 = make_float4(0.f, 0.f, 0.f, 0.f);
    float4 s2 = make_float4(0.f, 0.f, 0.f, 0.f);
    float4 s3 = make_float4(0.f, 0.f, 0.f, 0.f);
    #pragma unroll 4
    for (int k = 0; k < ITERS; ++k) {
        float4 v = xr[(size_t)k * GRID * C4];
        s1.x += v.x; s1.y += v.y; s1.z += v.z; s1.w += v.w;
        s2.x = fmaf(v.x, v.x, s2.x);
        s2.y = fmaf(v.y, v.y, s2.y);
        s2.z = fmaf(v.z, v.z, s2.z);
        s2.w = fmaf(v.w, v.w, s2.w);
        // x*log(x): guard x==0 (ref's p*log(p+eps) -> 0 there too)
        s3.x += (v.x > 0.f) ? v.x * __logf(v.x) : 0.f;
        s3.y += (v.y > 0.f) ? v.y * __logf(v.y) : 0.f;
        s3.z += (v.z > 0.f) ? v.z * __logf(v.z) : 0.f;
        s3.w += (v.w > 0.f) ? v.w * __logf(v.w) : 0.f;
    }

    // hierarchical merge: 64 slots -> chain depth GRID/NSLOT = 32 per address,
    // 3072 independent addresses overlap.
    float* dst = part + (size_t)(blockIdx.x & (NSLOT - 1)) * 3 * COLS + 4 * t;
    atomicAdd(dst + 0,            s1.x);
    atomicAdd(dst + 1,            s1.y);
    atomicAdd(dst + 2,            s1.z);
    atomicAdd(dst + 3,            s1.w);
    atomicAdd(dst + COLS + 0,     s2.x);
    atomicAdd(dst + COLS + 1,     s2.y);
    atomicAdd(dst + COLS + 2,     s2.z);
    atomicAdd(dst + COLS + 3,     s2.w);
    atomicAdd(dst + 2 * COLS + 0, s3.x);
    atomicAdd(dst + 2 * COLS + 1, s3.y);
    atomicAdd(dst + 2 * COLS + 2, s3.z);
    atomicAdd(dst + 2 * COLS + 3, s3.w);
}

// grid 4 x 256: column j folds its NSLOT partials into the per-column
// contribution, then block-reduces to bpart[blockIdx].
__global__ __launch_bounds__(256) void finalize_kernel(
    const float* __restrict__ part, float* __restrict__ bpart) {
    const int t = threadIdx.x;
    const int j = blockIdx.x * 256 + t;
    float a1 = 0.f, a2 = 0.f, a3 = 0.f;
    #pragma unroll 8
    for (int r = 0; r < NSLOT; ++r) {
        const float* p = part + (size_t)r * 3 * COLS + j;
        a1 += p[0];
        a2 += p[COLS];
        a3 += p[2 * COLS];
    }
    float n = fmaxf(sqrtf(a2), EPS_NORM);
    float contrib = (a3 - __logf(n) * a1) / n;

    #pragma unroll
    for (int o = 32; o > 0; o >>= 1) contrib += __shfl_down(contrib, o, 64);

    __shared__ float wsum[4];
    if ((t & 63) == 0) wsum[t >> 6] = contrib;
    __syncthreads();
    if (t == 0) bpart[blockIdx.x] = wsum[0] + wsum[1] + wsum[2] + wsum[3];
}

// 1 block x 64: fold the 4 block partials, negate + mean.
__global__ __launch_bounds__(64) void final_reduce_kernel(
    const float* __restrict__ bpart, float* __restrict__ out) {
    const int t = threadIdx.x;
    float a = (t < 4) ? bpart[t] : 0.f;
    #pragma unroll
    for (int o = 32; o > 0; o >>= 1) a += __shfl_down(a, o, 64);
    if (t == 0) out[0] = -a * (1.0f / (float)ROWS);
}

extern "C" void kernel_launch(void* const* d_in, const int* in_sizes, int n_in,
                              void* d_out, int out_size, void* d_ws, size_t ws_size,
                              hipStream_t stream) {
    const float* x = (const float*)d_in[0];
    float* out = (float*)d_out;
    float* ws = (float*)d_ws;
    float* part  = ws + WS_PART;
    float* bpart = ws + WS_BPART;

    // part is accumulated atomically -> zero it (ws is 0xAA-poisoned each call).
    hipMemsetAsync(part, 0, (size_t)NSLOT * 3 * COLS * sizeof(float), stream);

    fused_stats_kernel<<<GRID, 256, 0, stream>>>(x, part);
    finalize_kernel<<<COLS / 256, 256, 0, stream>>>(part, bpart);
    final_reduce_kernel<<<1, 64, 0, stream>>>(bpart, out);
}

// Round 5
// 381.950 us; speedup vs baseline: 1.2573x; 1.0595x over previous
//
#include <hip/hip_runtime.h>
#include <hip/hip_bf16.h>

// EntropyLoss: x (65536 x 1024) fp32.
//   norm2[j] = sum_i x[i][j]^2 ; n_j = max(sqrt(norm2), 1e-12)
//   out = -(1/R) * sum_ij (x/n) * log(x/n + 1e-8)
//
// One-pass sufficient statistics (log(p+1e-8) ~= log x - log n, error ~1e-5
// on output, threshold 0.38):
//   S1 = sum x, S2 = sum x^2, S3 = sum x*log(x)  (per column)
//   out = -(1/R) * sum_j (S3_j - log(n_j)*S1_j) / n_j
//
// R5 vs R2: NO ATOMICS in the main kernel. R2's 6.3M device-scope atomicAdds
// (12 per thread) ran at ~60M/s => ~90us tail that dominated the kernel
// (152us for a 268MB sweep = 1.8 TB/s effective). Now each block writes its
// 3x1024 partials as plain coalesced float4 stores to a private slot
// (part[2048][3][1024] = 25MB), reduced by a coalesced tree:
//   fused (2048 slots) -> reduce1 (64 slots) -> finalize (per-col contrib)
//   -> final (scalar).
// Also: no ws memset needed (everything written before read), unroll 8.
//
// Fixed harness floor (outside our control): ~247us/iter = 1GiB ws poison
// (~159us) + 256MiB input restore (~80us) + gaps.

#define ROWS  65536
#define COLS  1024
#define C4    (COLS / 4)
#define GRID  2048
#define ITERS (ROWS / GRID)   // 32
#define RED1  64              // reduce1 blocks; each folds GRID/RED1 = 32 slots

#define EPS_NORM 1e-12f

// ws layout (floats):
//   part : [GRID][3][COLS]  @ 0        (25.2 MB)
//   tmp  : [RED1][3][COLS]  @ WS_TMP   (768 KB)
//   bpart: [4]              @ WS_BPART
#define WS_TMP   (GRID * 3 * COLS)
#define WS_BPART (WS_TMP + RED1 * 3 * COLS)

__global__ __launch_bounds__(256) void fused_stats_kernel(
    const float* __restrict__ x, float* __restrict__ part) {
    const int t = threadIdx.x;
    // thread t owns cols 4t..4t+3 in every row; rows grid-strided so the
    // whole grid sweeps one contiguous 8MB window at a time.
    const float4* xr = reinterpret_cast<const float4*>(x)
                     + (size_t)blockIdx.x * C4 + t;

    float4 s1 = make_float4(0.f, 0.f, 0.f, 0.f);
    float4 s2 = make_float4(0.f, 0.f, 0.f, 0.f);
    float4 s3 = make_float4(0.f, 0.f, 0.f, 0.f);
    #pragma unroll 8
    for (int k = 0; k < ITERS; ++k) {
        float4 v = xr[(size_t)k * GRID * C4];
        s1.x += v.x; s1.y += v.y; s1.z += v.z; s1.w += v.w;
        s2.x = fmaf(v.x, v.x, s2.x);
        s2.y = fmaf(v.y, v.y, s2.y);
        s2.z = fmaf(v.z, v.z, s2.z);
        s2.w = fmaf(v.w, v.w, s2.w);
        // x*log(x): guard x==0 (ref's p*log(p+eps) -> 0 there too)
        s3.x += (v.x > 0.f) ? v.x * __logf(v.x) : 0.f;
        s3.y += (v.y > 0.f) ? v.y * __logf(v.y) : 0.f;
        s3.z += (v.z > 0.f) ? v.z * __logf(v.z) : 0.f;
        s3.w += (v.w > 0.f) ? v.w * __logf(v.w) : 0.f;
    }

    // Plain coalesced stores to a private per-block slot: zero atomics.
    float4* dst = reinterpret_cast<float4*>(part + (size_t)blockIdx.x * 3 * COLS) + t;
    dst[0]      = s1;
    dst[C4]     = s2;
    dst[2 * C4] = s3;
}

// RED1 blocks x 256: block b folds slots [32b, 32b+32) -> tmp[b], coalesced.
__global__ __launch_bounds__(256) void reduce1_kernel(
    const float* __restrict__ part, float* __restrict__ tmp) {
    const int t = threadIdx.x;
    const float4* p = reinterpret_cast<const float4*>(
        part + (size_t)blockIdx.x * (GRID / RED1) * 3 * COLS) + t;

    float4 a1 = make_float4(0.f, 0.f, 0.f, 0.f);
    float4 a2 = make_float4(0.f, 0.f, 0.f, 0.f);
    float4 a3 = make_float4(0.f, 0.f, 0.f, 0.f);
    #pragma unroll 4
    for (int s = 0; s < GRID / RED1; ++s) {
        const float4* ps = p + (size_t)s * 3 * C4;
        float4 v1 = ps[0], v2 = ps[C4], v3 = ps[2 * C4];
        a1.x += v1.x; a1.y += v1.y; a1.z += v1.z; a1.w += v1.w;
        a2.x += v2.x; a2.y += v2.y; a2.z += v2.z; a2.w += v2.w;
        a3.x += v3.x; a3.y += v3.y; a3.z += v3.z; a3.w += v3.w;
    }
    float4* d = reinterpret_cast<float4*>(tmp + (size_t)blockIdx.x * 3 * COLS) + t;
    d[0]      = a1;
    d[C4]     = a2;
    d[2 * C4] = a3;
}

// 4 blocks x 256: column j folds its RED1 partials into the per-column
// contribution, then block-reduces to bpart[blockIdx].
__global__ __launch_bounds__(256) void finalize_kernel(
    const float* __restrict__ tmp, float* __restrict__ bpart) {
    const int t = threadIdx.x;
    const int j = blockIdx.x * 256 + t;
    float a1 = 0.f, a2 = 0.f, a3 = 0.f;
    #pragma unroll 8
    for (int r = 0; r < RED1; ++r) {
        const float* p = tmp + (size_t)r * 3 * COLS + j;
        a1 += p[0];
        a2 += p[COLS];
        a3 += p[2 * COLS];
    }
    float n = fmaxf(sqrtf(a2), EPS_NORM);
    float contrib = (a3 - __logf(n) * a1) / n;

    #pragma unroll
    for (int o = 32; o > 0; o >>= 1) contrib += __shfl_down(contrib, o, 64);

    __shared__ float wsum[4];
    if ((t & 63) == 0) wsum[t >> 6] = contrib;
    __syncthreads();
    if (t == 0) bpart[blockIdx.x] = wsum[0] + wsum[1] + wsum[2] + wsum[3];
}

// 1 block x 64: fold the 4 block partials, negate + mean.
__global__ __launch_bounds__(64) void final_reduce_kernel(
    const float* __restrict__ bpart, float* __restrict__ out) {
    const int t = threadIdx.x;
    float a = (t < 4) ? bpart[t] : 0.f;
    #pragma unroll
    for (int o = 32; o > 0; o >>= 1) a += __shfl_down(a, o, 64);
    if (t == 0) out[0] = -a * (1.0f / (float)ROWS);
}

extern "C" void kernel_launch(void* const* d_in, const int* in_sizes, int n_in,
                              void* d_out, int out_size, void* d_ws, size_t ws_size,
                              hipStream_t stream) {
    const float* x = (const float*)d_in[0];
    float* out = (float*)d_out;
    float* ws = (float*)d_ws;
    float* part  = ws;
    float* tmp   = ws + WS_TMP;
    float* bpart = ws + WS_BPART;

    // No memset: every ws word consumed is written by an earlier kernel.
    fused_stats_kernel<<<GRID, 256, 0, stream>>>(x, part);
    reduce1_kernel<<<RED1, 256, 0, stream>>>(part, tmp);
    finalize_kernel<<<COLS / 256, 256, 0, stream>>>(tmp, bpart);
    final_reduce_kernel<<<1, 64, 0, stream>>>(bpart, out);
}